// Round 7
// baseline (396.441 us; speedup 1.0000x reference)
//
#include <hip/hip_runtime.h>
#include <hip/hip_cooperative_groups.h>
#include <math.h>

namespace cg = cooperative_groups;

#define NN 1296              // 36*36 nodes
#define OFF 40               // front pad (>=36, zeroed), keeps 16B alignment
#define TOT (OFF + NN + 40)  // 1376 floats per node-array
#define KMAX 240             // Chebyshev iteration cap
#define PXW 21               // waves per (b,co) plane: ceil(1296/64)

// ------- 3x3 SAME conv phase, one thread per (pixel, co); co wave-uniform ----
template<int CIN, int COUT, bool RELU>
__device__ __forceinline__ void conv_phase(int wid, int lane,
    const float* __restrict__ in, const float* __restrict__ wgt,
    const float* __restrict__ bias, float* __restrict__ out)
{
  if (wid >= 2 * COUT * PXW) return;
  const int px  = (wid % PXW) * 64 + lane;
  const int coV = (wid / PXW) % COUT;
  const int bV  = wid / (PXW * COUT);
  const int co  = __builtin_amdgcn_readfirstlane(coV);   // wave-uniform
  const int b   = __builtin_amdgcn_readfirstlane(bV);
  if (px >= NN) return;

  const int py = px / 36, pxx = px % 36;
  int offs[9]; float msk[9];
#pragma unroll
  for (int dy = 0; dy < 3; ++dy)
#pragma unroll
    for (int dx = 0; dx < 3; ++dx) {
      const int yy = py + dy - 1, xx = pxx + dx - 1;
      const bool ok = ((unsigned)yy < 36u) && ((unsigned)xx < 36u);
      offs[dy * 3 + dx] = ok ? (yy * 36 + xx) : 0;
      msk[dy * 3 + dx]  = ok ? 1.f : 0.f;
    }

  float acc = bias[co];
  const float* __restrict__ inp = in + (size_t)b * CIN * NN;
  const float* __restrict__ wB  = wgt + (size_t)co * CIN * 9;

#pragma unroll 8
  for (int ci = 0; ci < CIN; ++ci) {
    float v[9];
#pragma unroll
    for (int k9 = 0; k9 < 9; ++k9) v[k9] = msk[k9] * inp[ci * NN + offs[k9]];
#pragma unroll
    for (int k9 = 0; k9 < 9; ++k9) acc = fmaf(v[k9], wB[ci * 9 + k9], acc);
  }
  if (RELU) acc = fmaxf(acc, 0.f);
  out[(size_t)(b * COUT + co) * NN + px] = acc;
}

// ---- fused: 7 conv layers (grid-synced) -> edge weights -> Chebyshev solve --
__global__ __launch_bounds__(384) void fused_k(
    const float* __restrict__ xf, const float* __restrict__ up,
    const float* __restrict__ cw_in, const float* __restrict__ b_in,
    const float* __restrict__ cw_mid, const float* __restrict__ b_mid,
    const float* __restrict__ cw_out, const float* __restrict__ b_out,
    float* __restrict__ hb0, float* __restrict__ hb1,
    float* __restrict__ feat, float* __restrict__ out)
{
  cg::grid_group grid = cg::this_grid();
  const int tid  = threadIdx.x;
  const int gwid = (blockIdx.x * 384 + tid) >> 6;
  const int lane = tid & 63;

  // ---- conv chain, 7 phases, grid-synced ----
  conv_phase<3, 32, true>(gwid, lane, xf, cw_in, b_in, hb0);
  grid.sync();
  const float* src = hb0; float* dst = hb1;
#pragma unroll 1
  for (int i = 0; i < 5; ++i) {
    conv_phase<32, 32, true>(gwid, lane, src, cw_mid + i * 9216, b_mid + i * 32, dst);
    grid.sync();
    float* t = dst; dst = (float*)src; src = t;
  }
  conv_phase<32, 6, false>(gwid, lane, src, cw_out, b_out, feat);
  grid.sync();

  // ---- solver: blocks 0..5 only ----
  if (blockIdx.x >= 6) return;

  const int sys = blockIdx.x, b = sys / 3, ch = sys % 3;
  const int wave = tid >> 6;
  const bool act = tid < 324;
  const int qq = act ? tid : 0;
  const int i0 = OFF + 4 * qq;            // 16B-aligned LDS index

  __shared__ __align__(16) float ysL[TOT], ahL[TOT], avL[TOT], dA[TOT], dB[TOT];
  __shared__ float red[16];

  float u = up[0]; u = fminf(fmaxf(u, 0.001f), 1.0f);

  if (tid < OFF) {
    const int t2 = OFF + NN + tid;
    ysL[tid] = 0.f; ahL[tid] = 0.f; avL[tid] = 0.f; dA[tid] = 0.f; dB[tid] = 0.f;
    ysL[t2] = 0.f; ahL[t2] = 0.f; avL[t2] = 0.f; dA[t2] = 0.f; dB[t2] = 0.f;
  }

  const float* __restrict__ xfB = xf + (size_t)(b * 3 + ch) * NN;
  float wh4[4] = {0.f, 0.f, 0.f, 0.f}, wv4[4] = {0.f, 0.f, 0.f, 0.f};
  if (act) {
    *(float4*)&ysL[i0] = *(const float4*)&xfB[4 * qq];
    // inline edge weights from feat (replaces edgew kernel)
#pragma unroll
    for (int j = 0; j < 4; ++j) {
      const int n = 4 * qq + j;
      const int col = n % 36, row = n / 36;
      float sh = 0.f, sv = 0.f;
#pragma unroll
      for (int f = 0; f < 6; ++f) {
        const float* __restrict__ fp = feat + (size_t)(b * 6 + f) * NN;
        const float a = fp[n];
        if (col < 35) { const float d = a - fp[n + 1];  sh += d * d; }
        if (row < 35) { const float d = a - fp[n + 36]; sv += d * d; }
      }
      wh4[j] = (col < 35) ? expf(-sh * 1e4f) : 0.f;
      wv4[j] = (row < 35) ? expf(-sv * 1e4f) : 0.f;
    }
  }
  __syncthreads();

  float x[4] = {0.f, 0.f, 0.f, 0.f};

  for (int it = 0; it < 9; ++it) {
    // ---- P1: reweighted u-scaled edge coefficients from current y ----
    float4 yv = make_float4(0,0,0,0);
    float ah[4] = {0,0,0,0}, av[4] = {0,0,0,0};
    if (act) {
      yv = *(const float4*)&ysL[i0];
      const float yR = ysL[i0 + 4];
      const float4 yD = *(const float4*)&ysL[i0 + 36];
      ah[0] = u * wh4[0] / fmaxf(fabsf(yv.x - yv.y), 0.01f);
      ah[1] = u * wh4[1] / fmaxf(fabsf(yv.y - yv.z), 0.01f);
      ah[2] = u * wh4[2] / fmaxf(fabsf(yv.z - yv.w), 0.01f);
      ah[3] = u * wh4[3] / fmaxf(fabsf(yv.w - yR  ), 0.01f);
      av[0] = u * wv4[0] / fmaxf(fabsf(yv.x - yD.x), 0.01f);
      av[1] = u * wv4[1] / fmaxf(fabsf(yv.y - yD.y), 0.01f);
      av[2] = u * wv4[2] / fmaxf(fabsf(yv.z - yD.z), 0.01f);
      av[3] = u * wv4[3] / fmaxf(fabsf(yv.w - yD.w), 0.01f);
      *(float4*)&ahL[i0] = make_float4(ah[0], ah[1], ah[2], ah[3]);
      *(float4*)&avL[i0] = make_float4(av[0], av[1], av[2], av[3]);
    }
    __syncthreads();

    // ---- P2: stencil coeffs (regs), b -> dA, Gershgorin reduction ----
    float cL[4], cR[4], cU[4], cD[4], cc[4], bn[4];
    float mo = 0.f;
    if (act) {
      const float cl0 = ahL[i0 - 1];
      const float4 aU = *(const float4*)&avL[i0 - 36];
      cL[0] = cl0;  cL[1] = ah[0]; cL[2] = ah[1]; cL[3] = ah[2];
      cR[0] = ah[0]; cR[1] = ah[1]; cR[2] = ah[2]; cR[3] = ah[3];
      cU[0] = aU.x; cU[1] = aU.y; cU[2] = aU.z; cU[3] = aU.w;
      cD[0] = av[0]; cD[1] = av[1]; cD[2] = av[2]; cD[3] = av[3];
      bn[0] = yv.x; bn[1] = yv.y; bn[2] = yv.z; bn[3] = yv.w;
#pragma unroll
      for (int j = 0; j < 4; ++j) {
        const float offsum = cL[j] + cR[j] + cU[j] + cD[j];
        cc[j] = 1.f + offsum;
        mo = fmaxf(mo, offsum);
      }
      *(float4*)&dA[i0] = yv;
    } else {
#pragma unroll
      for (int j = 0; j < 4; ++j) { cL[j]=cR[j]=cU[j]=cD[j]=0.f; cc[j]=1.f; bn[j]=0.f; }
    }
#pragma unroll
    for (int o = 32; o >= 1; o >>= 1) mo = fmaxf(mo, __shfl_xor(mo, o));
    if ((tid & 63) == 0) red[wave] = mo;
    __syncthreads();
    if (tid == 0) {
      float m = red[0];
      for (int w = 1; w < 6; ++w) m = fmaxf(m, red[w]);
      red[8] = m;
    }
    __syncthreads();

    const float maxoff = red[8];
    const float theta = 1.f + maxoff;
    const float del   = fmaxf(maxoff, 1e-30f);
    const float sig1  = theta / del;
    float rho = del / theta;

    // adaptive iteration count: 2*rho_c^k <= ~7e-4
    const float kappa = 1.f + 2.f * maxoff;
    const float srk = sqrtf(kappa);
    const float rc  = (srk - 1.f) / (srk + 1.f);
    int kneed = (int)ceilf(8.0f / (-logf(rc)));
    kneed = (kneed < 3) ? 3 : (kneed > KMAX ? KMAX : kneed);

    // ---- P3: x0 = b, r0 = b - A b, d0 = r0/theta -> dB ----
    float r[4], d[4];
    if (act) {
      const float dl = dA[i0 - 1], dr = dA[i0 + 4];
      const float4 u4 = *(const float4*)&dA[i0 - 36];
      const float4 d4 = *(const float4*)&dA[i0 + 36];
      const float uu[4] = {u4.x, u4.y, u4.z, u4.w};
      const float dd[4] = {d4.x, d4.y, d4.z, d4.w};
#pragma unroll
      for (int j = 0; j < 4; ++j) {
        const float nl = (j == 0) ? dl : bn[j - 1];
        const float nr = (j == 3) ? dr : bn[j + 1];
        const float Ab = cc[j] * bn[j] - cL[j] * nl - cR[j] * nr
                       - cU[j] * uu[j] - cD[j] * dd[j];
        x[j] = bn[j];
        r[j] = bn[j] - Ab;
        d[j] = r[j] / theta;
      }
      *(float4*)&dB[i0] = make_float4(d[0], d[1], d[2], d[3]);
    } else {
#pragma unroll
      for (int j = 0; j < 4; ++j) { r[j] = 0.f; d[j] = 0.f; }
    }
    __syncthreads();

    // ---- P4: Chebyshev 3-term recurrence, halo-only LDS traffic ----
    float* dc = dB; float* dnx = dA;
    for (int k = 0; k < kneed; ++k) {
      const float rn = 1.f / (2.f * sig1 - rho);
      const float cd = rn * rho, cr = 2.f * rn / del;
      rho = rn;
      if (act) {
        const float dl = dc[i0 - 1], dr = dc[i0 + 4];
        const float4 u4 = *(const float4*)&dc[i0 - 36];
        const float4 d4 = *(const float4*)&dc[i0 + 36];
        const float uu[4] = {u4.x, u4.y, u4.z, u4.w};
        const float dd[4] = {d4.x, d4.y, d4.z, d4.w};
        float dn[4];
#pragma unroll
        for (int j = 0; j < 4; ++j) {
          const float nl = (j == 0) ? dl : d[j - 1];
          const float nr = (j == 3) ? dr : d[j + 1];
          const float Ad = cc[j] * d[j] - cL[j] * nl - cR[j] * nr
                         - cU[j] * uu[j] - cD[j] * dd[j];
          x[j] += d[j];
          r[j] -= Ad;
          dn[j] = cd * d[j] + cr * r[j];
        }
        *(float4*)&dnx[i0] = make_float4(dn[0], dn[1], dn[2], dn[3]);
#pragma unroll
        for (int j = 0; j < 4; ++j) d[j] = dn[j];
      }
      __syncthreads();
      float* t = dc; dc = dnx; dnx = t;
    }

    // ---- commit x as next iteration's y ----
    if (act) *(float4*)&ysL[i0] = make_float4(x[0], x[1], x[2], x[3]);
    __syncthreads();
  }

  if (act) *(float4*)&out[(size_t)(b * 3 + ch) * NN + 4 * qq]
      = make_float4(x[0], x[1], x[2], x[3]);
}

// =================== fallback path (R6 kernels, unchanged) ===================
template<int CIN, int COUT, bool RELU>
__global__ __launch_bounds__(256) void conv_pc_t(
    const float* __restrict__ in, const float* __restrict__ wgt,
    const float* __restrict__ bias, float* __restrict__ out)
{
  const int gid = blockIdx.x * 256 + threadIdx.x;
  conv_phase<CIN, COUT, RELU>(gid >> 6, gid & 63, in, wgt, bias, out);
}

__global__ __launch_bounds__(256) void edgew_k(const float* __restrict__ feat,
    float* __restrict__ wh, float* __restrict__ wv)
{
  const int b = blockIdx.y;
  const int n = blockIdx.x * 256 + threadIdx.x;
  if (n >= NN) return;
  const int col = n % 36, row = n / 36;
  float sh = 0.f, sv = 0.f;
#pragma unroll
  for (int f = 0; f < 6; ++f) {
    const float* __restrict__ fp = feat + (size_t)(b * 6 + f) * NN;
    const float a = fp[n];
    if (col < 35) { const float d = a - fp[n + 1];  sh += d * d; }
    if (row < 35) { const float d = a - fp[n + 36]; sv += d * d; }
  }
  wh[b * NN + n] = (col < 35) ? expf(-sh * 1e4f) : 0.f;
  wv[b * NN + n] = (row < 35) ? expf(-sv * 1e4f) : 0.f;
}

__global__ __launch_bounds__(384) void gtv_cheb_k(
    const float* __restrict__ xf, const float* __restrict__ up,
    const float* __restrict__ whg, const float* __restrict__ wvg,
    float* __restrict__ out)
{
  const int sys = blockIdx.x, b = sys / 3, ch = sys % 3;
  const int tid = threadIdx.x;
  const int wave = tid >> 6, lane = tid & 63;
  const bool act = tid < 324;
  const int qq = act ? tid : 0;
  const int i0 = OFF + 4 * qq;

  __shared__ __align__(16) float ysL[TOT], ahL[TOT], avL[TOT], dA[TOT], dB[TOT];
  __shared__ float red[16];

  float u = up[0]; u = fminf(fmaxf(u, 0.001f), 1.0f);

  if (tid < OFF) {
    const int t2 = OFF + NN + tid;
    ysL[tid] = 0.f; ahL[tid] = 0.f; avL[tid] = 0.f; dA[tid] = 0.f; dB[tid] = 0.f;
    ysL[t2] = 0.f; ahL[t2] = 0.f; avL[t2] = 0.f; dA[t2] = 0.f; dB[t2] = 0.f;
  }

  const float* __restrict__ xfB = xf + (size_t)(b * 3 + ch) * NN;
  float4 wh4 = make_float4(0.f, 0.f, 0.f, 0.f), wv4 = wh4;
  if (act) {
    *(float4*)&ysL[i0] = *(const float4*)&xfB[4 * qq];
    wh4 = *(const float4*)&whg[b * NN + 4 * qq];
    wv4 = *(const float4*)&wvg[b * NN + 4 * qq];
  }
  __syncthreads();

  float x[4] = {0.f, 0.f, 0.f, 0.f};

  for (int it = 0; it < 9; ++it) {
    float4 yv = make_float4(0,0,0,0);
    float ah[4] = {0,0,0,0}, av[4] = {0,0,0,0};
    if (act) {
      yv = *(const float4*)&ysL[i0];
      const float yR = ysL[i0 + 4];
      const float4 yD = *(const float4*)&ysL[i0 + 36];
      ah[0] = u * wh4.x / fmaxf(fabsf(yv.x - yv.y), 0.01f);
      ah[1] = u * wh4.y / fmaxf(fabsf(yv.y - yv.z), 0.01f);
      ah[2] = u * wh4.z / fmaxf(fabsf(yv.z - yv.w), 0.01f);
      ah[3] = u * wh4.w / fmaxf(fabsf(yv.w - yR  ), 0.01f);
      av[0] = u * wv4.x / fmaxf(fabsf(yv.x - yD.x), 0.01f);
      av[1] = u * wv4.y / fmaxf(fabsf(yv.y - yD.y), 0.01f);
      av[2] = u * wv4.z / fmaxf(fabsf(yv.z - yD.z), 0.01f);
      av[3] = u * wv4.w / fmaxf(fabsf(yv.w - yD.w), 0.01f);
      *(float4*)&ahL[i0] = make_float4(ah[0], ah[1], ah[2], ah[3]);
      *(float4*)&avL[i0] = make_float4(av[0], av[1], av[2], av[3]);
    }
    __syncthreads();

    float cL[4], cR[4], cU[4], cD[4], cc[4], bn[4];
    float mo = 0.f;
    if (act) {
      const float cl0 = ahL[i0 - 1];
      const float4 aU = *(const float4*)&avL[i0 - 36];
      cL[0] = cl0;  cL[1] = ah[0]; cL[2] = ah[1]; cL[3] = ah[2];
      cR[0] = ah[0]; cR[1] = ah[1]; cR[2] = ah[2]; cR[3] = ah[3];
      cU[0] = aU.x; cU[1] = aU.y; cU[2] = aU.z; cU[3] = aU.w;
      cD[0] = av[0]; cD[1] = av[1]; cD[2] = av[2]; cD[3] = av[3];
      bn[0] = yv.x; bn[1] = yv.y; bn[2] = yv.z; bn[3] = yv.w;
#pragma unroll
      for (int j = 0; j < 4; ++j) {
        const float offsum = cL[j] + cR[j] + cU[j] + cD[j];
        cc[j] = 1.f + offsum;
        mo = fmaxf(mo, offsum);
      }
      *(float4*)&dA[i0] = yv;
    } else {
#pragma unroll
      for (int j = 0; j < 4; ++j) { cL[j]=cR[j]=cU[j]=cD[j]=0.f; cc[j]=1.f; bn[j]=0.f; }
    }
#pragma unroll
    for (int o = 32; o >= 1; o >>= 1) mo = fmaxf(mo, __shfl_xor(mo, o));
    if (lane == 0) red[wave] = mo;
    __syncthreads();
    if (tid == 0) {
      float m = red[0];
      for (int w = 1; w < 6; ++w) m = fmaxf(m, red[w]);
      red[8] = m;
    }
    __syncthreads();

    const float maxoff = red[8];
    const float theta = 1.f + maxoff;
    const float del   = fmaxf(maxoff, 1e-30f);
    const float sig1  = theta / del;
    float rho = del / theta;

    const float kappa = 1.f + 2.f * maxoff;
    const float srk = sqrtf(kappa);
    const float rc  = (srk - 1.f) / (srk + 1.f);
    int kneed = (int)ceilf(8.0f / (-logf(rc)));
    kneed = (kneed < 3) ? 3 : (kneed > KMAX ? KMAX : kneed);

    float r[4], d[4];
    if (act) {
      const float dl = dA[i0 - 1], dr = dA[i0 + 4];
      const float4 u4 = *(const float4*)&dA[i0 - 36];
      const float4 d4 = *(const float4*)&dA[i0 + 36];
      const float uu[4] = {u4.x, u4.y, u4.z, u4.w};
      const float dd[4] = {d4.x, d4.y, d4.z, d4.w};
#pragma unroll
      for (int j = 0; j < 4; ++j) {
        const float nl = (j == 0) ? dl : bn[j - 1];
        const float nr = (j == 3) ? dr : bn[j + 1];
        const float Ab = cc[j] * bn[j] - cL[j] * nl - cR[j] * nr
                       - cU[j] * uu[j] - cD[j] * dd[j];
        x[j] = bn[j];
        r[j] = bn[j] - Ab;
        d[j] = r[j] / theta;
      }
      *(float4*)&dB[i0] = make_float4(d[0], d[1], d[2], d[3]);
    } else {
#pragma unroll
      for (int j = 0; j < 4; ++j) { r[j] = 0.f; d[j] = 0.f; }
    }
    __syncthreads();

    float* dc = dB; float* dnx = dA;
    for (int k = 0; k < kneed; ++k) {
      const float rn = 1.f / (2.f * sig1 - rho);
      const float cd = rn * rho, cr = 2.f * rn / del;
      rho = rn;
      if (act) {
        const float dl = dc[i0 - 1], dr = dc[i0 + 4];
        const float4 u4 = *(const float4*)&dc[i0 - 36];
        const float4 d4 = *(const float4*)&dc[i0 + 36];
        const float uu[4] = {u4.x, u4.y, u4.z, u4.w};
        const float dd[4] = {d4.x, d4.y, d4.z, d4.w};
        float dn[4];
#pragma unroll
        for (int j = 0; j < 4; ++j) {
          const float nl = (j == 0) ? dl : d[j - 1];
          const float nr = (j == 3) ? dr : d[j + 1];
          const float Ad = cc[j] * d[j] - cL[j] * nl - cR[j] * nr
                         - cU[j] * uu[j] - cD[j] * dd[j];
          x[j] += d[j];
          r[j] -= Ad;
          dn[j] = cd * d[j] + cr * r[j];
        }
        *(float4*)&dnx[i0] = make_float4(dn[0], dn[1], dn[2], dn[3]);
#pragma unroll
        for (int j = 0; j < 4; ++j) d[j] = dn[j];
      }
      __syncthreads();
      float* t = dc; dc = dnx; dnx = t;
    }

    if (act) *(float4*)&ysL[i0] = make_float4(x[0], x[1], x[2], x[3]);
    __syncthreads();
  }

  if (act) *(float4*)&out[(size_t)(b * 3 + ch) * NN + 4 * qq]
      = make_float4(x[0], x[1], x[2], x[3]);
}

// ----------------------------------------------------------------------------
extern "C" void kernel_launch(void* const* d_in, const int* in_sizes, int n_in,
                              void* d_out, int out_size, void* d_ws, size_t ws_size,
                              hipStream_t stream) {
  const float* xf     = (const float*)d_in[0];   // [2,3,36,36]
  const float* up     = (const float*)d_in[1];   // [1]
  const float* cw_in  = (const float*)d_in[3];   // [32,3,3,3]
  const float* b_in   = (const float*)d_in[4];   // [32]
  const float* cw_mid = (const float*)d_in[5];   // [5,32,32,3,3]
  const float* b_mid  = (const float*)d_in[6];   // [5,32]
  const float* cw_out = (const float*)d_in[7];   // [6,32,3,3]
  const float* b_out  = (const float*)d_in[8];   // [6]

  float* ws   = (float*)d_ws;
  float* wh   = ws;                   // 2592
  float* wv   = ws + 2592;            // 2592
  float* hb0  = ws + 5184;            // 82944
  float* hb1  = hb0 + 82944;          // 82944
  float* feat = hb1 + 82944;          // 15552
  float* outp = (float*)d_out;

  void* args[] = {
    (void*)&xf, (void*)&up, (void*)&cw_in, (void*)&b_in, (void*)&cw_mid,
    (void*)&b_mid, (void*)&cw_out, (void*)&b_out, (void*)&hb0, (void*)&hb1,
    (void*)&feat, (void*)&outp
  };
  hipError_t e = hipLaunchCooperativeKernel((const void*)fused_k,
                                            dim3(224), dim3(384), args, 0, stream);
  if (e != hipSuccess) {
    // fallback: R6 multi-dispatch path
    const int blk32 = (2 * 32 * PXW) / 4;
    const int blk6  = (2 * 6 * PXW + 3) / 4;
    conv_pc_t<3, 32, true><<<dim3(blk32), dim3(256), 0, stream>>>(xf, cw_in, b_in, hb0);
    const float* src = hb0; float* dst = hb1;
    for (int i = 0; i < 5; ++i) {
      conv_pc_t<32, 32, true><<<dim3(blk32), dim3(256), 0, stream>>>(
          src, cw_mid + i * 9216, b_mid + i * 32, dst);
      const float* t = dst; dst = (float*)src; src = t;
    }
    conv_pc_t<32, 6, false><<<dim3(blk6), dim3(256), 0, stream>>>(src, cw_out, b_out, feat);
    edgew_k<<<dim3(6, 2), dim3(256), 0, stream>>>(feat, wh, wv);
    gtv_cheb_k<<<dim3(6), dim3(384), 0, stream>>>(xf, up, wh, wv, outp);
  }
}

// Round 8
// 120.114 us; speedup vs baseline: 3.3005x; 3.3005x over previous
//
#include <hip/hip_runtime.h>
#include <math.h>

#define NN 1296              // 36*36 nodes
#define OFF 40               // front pad (>=36, zeroed), keeps 16B alignment
#define TOT (OFF + NN + 40)  // 1376 floats per node-array
#define KMAX 240             // Chebyshev iteration cap
#define PXW 21               // 64-px groups per image: ceil(1296/64)

// ---------------- conv1: 3->32, one thread per (px, co) ----------------------
__global__ __launch_bounds__(256) void conv_in_k(
    const float* __restrict__ in, const float* __restrict__ wgt,
    const float* __restrict__ bias, float* __restrict__ out)
{
  const int gid = blockIdx.x * 256 + threadIdx.x;
  const int wid = gid >> 6, lane = gid & 63;
  if (wid >= 2 * 32 * PXW) return;
  const int px = (wid % PXW) * 64 + lane;
  const int co = __builtin_amdgcn_readfirstlane((wid / PXW) % 32);
  const int b  = __builtin_amdgcn_readfirstlane(wid / (PXW * 32));
  if (px >= NN) return;

  const int py = px / 36, pxx = px % 36;
  int offs[9]; float msk[9];
#pragma unroll
  for (int dy = 0; dy < 3; ++dy)
#pragma unroll
    for (int dx = 0; dx < 3; ++dx) {
      const int yy = py + dy - 1, xx = pxx + dx - 1;
      const bool okp = ((unsigned)yy < 36u) && ((unsigned)xx < 36u);
      offs[dy * 3 + dx] = okp ? (yy * 36 + xx) : 0;
      msk[dy * 3 + dx]  = okp ? 1.f : 0.f;
    }

  float acc = bias[co];
  const float* __restrict__ inp = in + (size_t)b * 3 * NN;
  const float* __restrict__ wB  = wgt + (size_t)co * 3 * 9;
#pragma unroll
  for (int ci = 0; ci < 3; ++ci) {
    float v[9];
#pragma unroll
    for (int k9 = 0; k9 < 9; ++k9) v[k9] = msk[k9] * inp[ci * NN + offs[k9]];
#pragma unroll
    for (int k9 = 0; k9 < 9; ++k9) acc = fmaf(v[k9], wB[ci * 9 + k9], acc);
  }
  out[(size_t)(b * 32 + co) * NN + px] = fmaxf(acc, 0.f);
}

// -------- 32->COUT conv, 4-way ci split: thread = (px, ci-quarter) -----------
// Block = one (b, co, px-group): 256 threads = 64 px x 4 ci-quarters.
// 72 loads + 72 FMA per thread, LDS cross-quarter reduce.
template<int COUT, bool RELU>
__global__ __launch_bounds__(256) void conv_mid_k(
    const float* __restrict__ in, const float* __restrict__ wgt,
    const float* __restrict__ bias, float* __restrict__ out)
{
  const int blk = blockIdx.x;
  const int pxg = blk % PXW;
  const int co  = (blk / PXW) % COUT;
  const int b   = blk / (PXW * COUT);
  const int lane = threadIdx.x & 63;
  const int ciq  = threadIdx.x >> 6;       // 0..3
  const int px   = pxg * 64 + lane;
  const bool ok  = px < NN;

  __shared__ float part[4][64];

  float acc = 0.f;
  if (ok) {
    const int py = px / 36, pxx = px % 36;
    int offs[9]; float msk[9];
#pragma unroll
    for (int dy = 0; dy < 3; ++dy)
#pragma unroll
      for (int dx = 0; dx < 3; ++dx) {
        const int yy = py + dy - 1, xx = pxx + dx - 1;
        const bool okp = ((unsigned)yy < 36u) && ((unsigned)xx < 36u);
        offs[dy * 3 + dx] = okp ? (yy * 36 + xx) : 0;
        msk[dy * 3 + dx]  = okp ? 1.f : 0.f;
      }
    const float* __restrict__ inp = in + ((size_t)b * 32 + ciq * 8) * NN;
    const float* __restrict__ wB  = wgt + ((size_t)co * 32 + ciq * 8) * 9;
#pragma unroll
    for (int ci = 0; ci < 8; ++ci) {
      float v[9];
#pragma unroll
      for (int k9 = 0; k9 < 9; ++k9) v[k9] = msk[k9] * inp[ci * NN + offs[k9]];
#pragma unroll
      for (int k9 = 0; k9 < 9; ++k9) acc = fmaf(v[k9], wB[ci * 9 + k9], acc);
    }
  }
  part[ciq][lane] = acc;
  __syncthreads();
  if (threadIdx.x < 64 && ok) {
    float s = part[0][lane] + part[1][lane] + part[2][lane] + part[3][lane]
            + bias[co];
    if (RELU) s = fmaxf(s, 0.f);
    out[((size_t)b * COUT + co) * NN + px] = s;
  }
}

// ---- 9x { reweight -> residual-adaptive Chebyshev solve of (I+uL)x = y } ----
// One block per (b,c). 324 act threads x 4 row-aligned nodes. Edge weights
// computed inline from feat (no edgew dispatch). lambda_max via
// min(Gershgorin 2*d_max, Anderson-Morley max_edge(d_i+d_j)); iteration count
// sized to the ACTUAL initial residual: 2*rho_c^k*||r0|| <= ~1e-3-ish.
__global__ __launch_bounds__(384) void gtv_k(
    const float* __restrict__ xf, const float* __restrict__ up,
    const float* __restrict__ feat, float* __restrict__ out)
{
  const int sys = blockIdx.x, b = sys / 3, ch = sys % 3;
  const int tid = threadIdx.x;
  const int wave = tid >> 6, lane = tid & 63;
  const bool act = tid < 324;
  const int qq = act ? tid : 0;
  const int i0 = OFF + 4 * qq;

  __shared__ __align__(16) float ysL[TOT], ahL[TOT], avL[TOT],
                                 dA[TOT], dB[TOT], dgL[TOT];
  __shared__ float red[16];

  float u = up[0]; u = fminf(fmaxf(u, 0.001f), 1.0f);

  if (tid < OFF) {
    const int t2 = OFF + NN + tid;
    ysL[tid] = 0.f; ahL[tid] = 0.f; avL[tid] = 0.f;
    dA[tid] = 0.f; dB[tid] = 0.f; dgL[tid] = 0.f;
    ysL[t2] = 0.f; ahL[t2] = 0.f; avL[t2] = 0.f;
    dA[t2] = 0.f; dB[t2] = 0.f; dgL[t2] = 0.f;
  }

  const float* __restrict__ xfB = xf + (size_t)(b * 3 + ch) * NN;
  float wh4[4] = {0.f, 0.f, 0.f, 0.f}, wv4[4] = {0.f, 0.f, 0.f, 0.f};
  if (act) {
    *(float4*)&ysL[i0] = *(const float4*)&xfB[4 * qq];
    // inline edge weights from feat
#pragma unroll
    for (int j = 0; j < 4; ++j) {
      const int n = 4 * qq + j;
      const int col = n % 36, row = n / 36;
      float sh = 0.f, sv = 0.f;
#pragma unroll
      for (int f = 0; f < 6; ++f) {
        const float* __restrict__ fp = feat + (size_t)(b * 6 + f) * NN;
        const float a = fp[n];
        if (col < 35) { const float d = a - fp[n + 1];  sh += d * d; }
        if (row < 35) { const float d = a - fp[n + 36]; sv += d * d; }
      }
      wh4[j] = (col < 35) ? expf(-sh * 1e4f) : 0.f;
      wv4[j] = (row < 35) ? expf(-sv * 1e4f) : 0.f;
    }
  }
  __syncthreads();

  float x[4] = {0.f, 0.f, 0.f, 0.f};

  for (int it = 0; it < 9; ++it) {
    // ---- P1: u-scaled reweighted edge coefficients from current y ----
    float4 yv = make_float4(0,0,0,0);
    float ah[4] = {0,0,0,0}, av[4] = {0,0,0,0};
    if (act) {
      yv = *(const float4*)&ysL[i0];
      const float yR = ysL[i0 + 4];
      const float4 yD = *(const float4*)&ysL[i0 + 36];
      ah[0] = u * wh4[0] / fmaxf(fabsf(yv.x - yv.y), 0.01f);
      ah[1] = u * wh4[1] / fmaxf(fabsf(yv.y - yv.z), 0.01f);
      ah[2] = u * wh4[2] / fmaxf(fabsf(yv.z - yv.w), 0.01f);
      ah[3] = u * wh4[3] / fmaxf(fabsf(yv.w - yR  ), 0.01f);
      av[0] = u * wv4[0] / fmaxf(fabsf(yv.x - yD.x), 0.01f);
      av[1] = u * wv4[1] / fmaxf(fabsf(yv.y - yD.y), 0.01f);
      av[2] = u * wv4[2] / fmaxf(fabsf(yv.z - yD.z), 0.01f);
      av[3] = u * wv4[3] / fmaxf(fabsf(yv.w - yD.w), 0.01f);
      *(float4*)&ahL[i0] = make_float4(ah[0], ah[1], ah[2], ah[3]);
      *(float4*)&avL[i0] = make_float4(av[0], av[1], av[2], av[3]);
    }
    __syncthreads();                                         // B1

    // ---- P2: stencil coeffs, b -> dA, degrees -> dgL, Gershgorin max ----
    float cL[4], cR[4], cU[4], cD[4], cc[4], bn[4], os[4];
    float mo = 0.f;
    if (act) {
      const float cl0 = ahL[i0 - 1];
      const float4 aU = *(const float4*)&avL[i0 - 36];
      cL[0] = cl0;  cL[1] = ah[0]; cL[2] = ah[1]; cL[3] = ah[2];
      cR[0] = ah[0]; cR[1] = ah[1]; cR[2] = ah[2]; cR[3] = ah[3];
      cU[0] = aU.x; cU[1] = aU.y; cU[2] = aU.z; cU[3] = aU.w;
      cD[0] = av[0]; cD[1] = av[1]; cD[2] = av[2]; cD[3] = av[3];
      bn[0] = yv.x; bn[1] = yv.y; bn[2] = yv.z; bn[3] = yv.w;
#pragma unroll
      for (int j = 0; j < 4; ++j) {
        os[j] = cL[j] + cR[j] + cU[j] + cD[j];
        cc[j] = 1.f + os[j];
        mo = fmaxf(mo, os[j]);
      }
      *(float4*)&dA[i0]  = yv;
      *(float4*)&dgL[i0] = make_float4(os[0], os[1], os[2], os[3]);
    } else {
#pragma unroll
      for (int j = 0; j < 4; ++j) {
        cL[j]=cR[j]=cU[j]=cD[j]=0.f; cc[j]=1.f; bn[j]=0.f; os[j]=0.f;
      }
    }
#pragma unroll
    for (int o = 32; o >= 1; o >>= 1) mo = fmaxf(mo, __shfl_xor(mo, o));
    if (lane == 0) red[wave] = mo;
    __syncthreads();                                         // B2

    // ---- P2b: Anderson-Morley edge bound max_edge(d_i + d_j) ----
    float me = 0.f;
    if (act) {
      const float dnx3 = dgL[i0 + 4];
      const float4 dwn = *(const float4*)&dgL[i0 + 36];
      const float dn_[4] = { os[1], os[2], os[3], dnx3 };
      const float dd_[4] = { dwn.x, dwn.y, dwn.z, dwn.w };
#pragma unroll
      for (int j = 0; j < 4; ++j)
        me = fmaxf(me, os[j] + fmaxf(dn_[j], dd_[j]));
    }
#pragma unroll
    for (int o = 32; o >= 1; o >>= 1) me = fmaxf(me, __shfl_xor(me, o));
    if (lane == 0) red[8 + wave] = me;
    __syncthreads();                                         // B3
    if (tid == 0) {
      float m1 = red[0], m2 = red[8];
      for (int w = 1; w < 6; ++w) {
        m1 = fmaxf(m1, red[w]); m2 = fmaxf(m2, red[8 + w]);
      }
      red[14] = fminf(2.f * m1, m2);     // lambda_max(uL) upper bound
    }
    __syncthreads();                                         // B4

    const float lmaxL = red[14];
    const float h     = 0.5f * lmaxL;
    const float theta = 1.f + h;
    const float del   = fmaxf(h, 1e-30f);
    const float sig1  = theta / del;
    const float rho0  = del / theta;
    const float kappa = 1.f + lmaxL;
    const float srk   = sqrtf(kappa);
    const float rc    = (srk - 1.f) / (srk + 1.f);

    // ---- P3: x0 = b, r0 = b - A b, d0 = r0/theta -> dB; reduce ||r0||inf ----
    float r[4], d[4];
    float rmx = 0.f;
    if (act) {
      const float dl = dA[i0 - 1], dr = dA[i0 + 4];
      const float4 u4 = *(const float4*)&dA[i0 - 36];
      const float4 d4 = *(const float4*)&dA[i0 + 36];
      const float uu[4] = {u4.x, u4.y, u4.z, u4.w};
      const float dd[4] = {d4.x, d4.y, d4.z, d4.w};
#pragma unroll
      for (int j = 0; j < 4; ++j) {
        const float nl = (j == 0) ? dl : bn[j - 1];
        const float nr = (j == 3) ? dr : bn[j + 1];
        const float Ab = cc[j] * bn[j] - cL[j] * nl - cR[j] * nr
                       - cU[j] * uu[j] - cD[j] * dd[j];
        x[j] = bn[j];
        r[j] = bn[j] - Ab;
        d[j] = r[j] / theta;
        rmx = fmaxf(rmx, fabsf(r[j]));
      }
      *(float4*)&dB[i0] = make_float4(d[0], d[1], d[2], d[3]);
    } else {
#pragma unroll
      for (int j = 0; j < 4; ++j) { r[j] = 0.f; d[j] = 0.f; x[j] = 0.f; }
    }
#pragma unroll
    for (int o = 32; o >= 1; o >>= 1) rmx = fmaxf(rmx, __shfl_xor(rmx, o));
    if (lane == 0) red[wave] = rmx;
    __syncthreads();                                         // B5
    if (tid == 0) {
      float m = red[0];
      for (int w = 1; w < 6; ++w) m = fmaxf(m, red[w]);
      red[9] = m;
    }
    __syncthreads();                                         // B6

    const float rmax = red[9];
    int kneed;
    if (rmax <= 5e-4f) kneed = 0;                 // already converged
    else if (rc < 1e-10f) kneed = 1;
    else {
      kneed = (int)ceilf((9.0f + logf(rmax)) / (-logf(rc)));
      kneed = (kneed < 1) ? 1 : (kneed > KMAX ? KMAX : kneed);
    }

    // ---- P4: Chebyshev 3-term recurrence, halo-only LDS traffic ----
    float rho = rho0;
    float* dc = dB; float* dnx = dA;
    for (int k = 0; k < kneed; ++k) {
      const float rn = 1.f / (2.f * sig1 - rho);
      const float cd = rn * rho, cr = 2.f * rn / del;
      rho = rn;
      if (act) {
        const float dl = dc[i0 - 1], dr = dc[i0 + 4];
        const float4 u4 = *(const float4*)&dc[i0 - 36];
        const float4 d4 = *(const float4*)&dc[i0 + 36];
        const float uu[4] = {u4.x, u4.y, u4.z, u4.w};
        const float dd[4] = {d4.x, d4.y, d4.z, d4.w};
        float dn[4];
#pragma unroll
        for (int j = 0; j < 4; ++j) {
          const float nl = (j == 0) ? dl : d[j - 1];
          const float nr = (j == 3) ? dr : d[j + 1];
          const float Ad = cc[j] * d[j] - cL[j] * nl - cR[j] * nr
                         - cU[j] * uu[j] - cD[j] * dd[j];
          x[j] += d[j];
          r[j] -= Ad;
          dn[j] = cd * d[j] + cr * r[j];
        }
        *(float4*)&dnx[i0] = make_float4(dn[0], dn[1], dn[2], dn[3]);
#pragma unroll
        for (int j = 0; j < 4; ++j) d[j] = dn[j];
      }
      __syncthreads();
      float* t = dc; dc = dnx; dnx = t;
    }

    // ---- commit x as next iteration's y ----
    if (act) *(float4*)&ysL[i0] = make_float4(x[0], x[1], x[2], x[3]);
    __syncthreads();                                         // B7
  }

  if (act) *(float4*)&out[(size_t)(b * 3 + ch) * NN + 4 * qq]
      = make_float4(x[0], x[1], x[2], x[3]);
}

// ----------------------------------------------------------------------------
extern "C" void kernel_launch(void* const* d_in, const int* in_sizes, int n_in,
                              void* d_out, int out_size, void* d_ws, size_t ws_size,
                              hipStream_t stream) {
  const float* xf     = (const float*)d_in[0];   // [2,3,36,36]
  const float* up     = (const float*)d_in[1];   // [1]
  const float* cw_in  = (const float*)d_in[3];   // [32,3,3,3]
  const float* b_in   = (const float*)d_in[4];   // [32]
  const float* cw_mid = (const float*)d_in[5];   // [5,32,32,3,3]
  const float* b_mid  = (const float*)d_in[6];   // [5,32]
  const float* cw_out = (const float*)d_in[7];   // [6,32,3,3]
  const float* b_out  = (const float*)d_in[8];   // [6]

  float* ws   = (float*)d_ws;
  float* hb0  = ws;                   // 2*32*1296 = 82944
  float* hb1  = hb0 + 82944;          // 82944
  float* feat = hb1 + 82944;          // 2*6*1296 = 15552

  conv_in_k<<<dim3(336), dim3(256), 0, stream>>>(xf, cw_in, b_in, hb0);
  const float* src = hb0; float* dst = hb1;
  for (int i = 0; i < 5; ++i) {
    conv_mid_k<32, true><<<dim3(2 * 32 * PXW), dim3(256), 0, stream>>>(
        src, cw_mid + i * 9216, b_mid + i * 32, dst);
    const float* t = dst; dst = (float*)src; src = t;
  }
  conv_mid_k<6, false><<<dim3(2 * 6 * PXW), dim3(256), 0, stream>>>(
      src, cw_out, b_out, feat);

  gtv_k<<<dim3(6), dim3(384), 0, stream>>>(xf, up, feat, (float*)d_out);
}

// Round 9
// 117.441 us; speedup vs baseline: 3.3757x; 1.0228x over previous
//
#include <hip/hip_runtime.h>
#include <math.h>

#define NN 1296              // 36*36 nodes
#define OFF 40               // front pad (>=36, zeroed), keeps 16B alignment
#define TOT (OFF + NN + 40)  // 1376 floats per node-array
#define KMAX 240             // Chebyshev iteration cap
#define PXW 21               // 64-px groups per image: ceil(1296/64)

// ---------------- conv1: 3->32, one thread per (px, co) ----------------------
__global__ __launch_bounds__(256) void conv_in_k(
    const float* __restrict__ in, const float* __restrict__ wgt,
    const float* __restrict__ bias, float* __restrict__ out)
{
  const int gid = blockIdx.x * 256 + threadIdx.x;
  const int wid = gid >> 6, lane = gid & 63;
  if (wid >= 2 * 32 * PXW) return;
  const int px = (wid % PXW) * 64 + lane;
  const int co = __builtin_amdgcn_readfirstlane((wid / PXW) % 32);
  const int b  = __builtin_amdgcn_readfirstlane(wid / (PXW * 32));
  if (px >= NN) return;

  const int py = px / 36, pxx = px % 36;
  int offs[9]; float msk[9];
#pragma unroll
  for (int dy = 0; dy < 3; ++dy)
#pragma unroll
    for (int dx = 0; dx < 3; ++dx) {
      const int yy = py + dy - 1, xx = pxx + dx - 1;
      const bool okp = ((unsigned)yy < 36u) && ((unsigned)xx < 36u);
      offs[dy * 3 + dx] = okp ? (yy * 36 + xx) : 0;
      msk[dy * 3 + dx]  = okp ? 1.f : 0.f;
    }

  float acc = bias[co];
  const float* __restrict__ inp = in + (size_t)b * 3 * NN;
  const float* __restrict__ wB  = wgt + (size_t)co * 3 * 9;
#pragma unroll
  for (int ci = 0; ci < 3; ++ci) {
    float v[9];
#pragma unroll
    for (int k9 = 0; k9 < 9; ++k9) v[k9] = msk[k9] * inp[ci * NN + offs[k9]];
#pragma unroll
    for (int k9 = 0; k9 < 9; ++k9) acc = fmaf(v[k9], wB[ci * 9 + k9], acc);
  }
  out[(size_t)(b * 32 + co) * NN + px] = fmaxf(acc, 0.f);
}

// ---- 32->32 conv, co-octet in registers: block=(b,cog,pxg), wave=ci-octet ----
// Each thread: 72 loads reused across 8 co (576 FMA), 4-way LDS reduce.
// 8x less L2 traffic than per-(px,co) form.
__global__ __launch_bounds__(256) void conv_mid2_k(
    const float* __restrict__ in, const float* __restrict__ wgt,
    const float* __restrict__ bias, float* __restrict__ out)
{
  const int blk = blockIdx.x;
  const int pxg = blk % PXW;
  const int cog = (blk / PXW) & 3;                 // co-octet 0..3
  const int b   = blk / (PXW * 4);
  const int lane = threadIdx.x & 63;
  const int ciq  = __builtin_amdgcn_readfirstlane(threadIdx.x >> 6); // wave id
  const int px   = pxg * 64 + lane;
  const bool ok  = px < NN;

  __shared__ float part[4][8][64];

  float acc[8] = {0.f, 0.f, 0.f, 0.f, 0.f, 0.f, 0.f, 0.f};
  if (ok) {
    const int py = px / 36, pxx = px % 36;
    int offs[9]; float msk[9];
#pragma unroll
    for (int dy = 0; dy < 3; ++dy)
#pragma unroll
      for (int dx = 0; dx < 3; ++dx) {
        const int yy = py + dy - 1, xx = pxx + dx - 1;
        const bool okp = ((unsigned)yy < 36u) && ((unsigned)xx < 36u);
        offs[dy * 3 + dx] = okp ? (yy * 36 + xx) : 0;
        msk[dy * 3 + dx]  = okp ? 1.f : 0.f;
      }
    const float* __restrict__ inp = in + ((size_t)b * 32 + ciq * 8) * NN;
    // w[(co)(ci_glob)(k)] with co = cog*8+t, ci_glob = ciq*8+ci  (wave-uniform)
    const float* __restrict__ wB = wgt + ((size_t)(cog * 8) * 32 + ciq * 8) * 9;
#pragma unroll
    for (int ci = 0; ci < 8; ++ci) {
      float v[9];
#pragma unroll
      for (int k9 = 0; k9 < 9; ++k9) v[k9] = msk[k9] * inp[ci * NN + offs[k9]];
#pragma unroll
      for (int t = 0; t < 8; ++t)
#pragma unroll
        for (int k9 = 0; k9 < 9; ++k9)
          acc[t] = fmaf(v[k9], wB[(t * 32 + ci) * 9 + k9], acc[t]);
    }
  }
#pragma unroll
  for (int t = 0; t < 8; ++t) part[ciq][t][lane] = acc[t];
  __syncthreads();
  if (ok) {
#pragma unroll
    for (int tt = 0; tt < 2; ++tt) {
      const int t = ciq + tt * 4;
      float s = part[0][t][lane] + part[1][t][lane]
              + part[2][t][lane] + part[3][t][lane] + bias[cog * 8 + t];
      s = fmaxf(s, 0.f);
      out[((size_t)b * 32 + cog * 8 + t) * NN + px] = s;
    }
  }
}

// -------- 32->COUT conv, 4-way ci split (kept for the 32->6 output layer) ----
template<int COUT, bool RELU>
__global__ __launch_bounds__(256) void conv_mid_k(
    const float* __restrict__ in, const float* __restrict__ wgt,
    const float* __restrict__ bias, float* __restrict__ out)
{
  const int blk = blockIdx.x;
  const int pxg = blk % PXW;
  const int co  = (blk / PXW) % COUT;
  const int b   = blk / (PXW * COUT);
  const int lane = threadIdx.x & 63;
  const int ciq  = threadIdx.x >> 6;       // 0..3
  const int px   = pxg * 64 + lane;
  const bool ok  = px < NN;

  __shared__ float part[4][64];

  float acc = 0.f;
  if (ok) {
    const int py = px / 36, pxx = px % 36;
    int offs[9]; float msk[9];
#pragma unroll
    for (int dy = 0; dy < 3; ++dy)
#pragma unroll
      for (int dx = 0; dx < 3; ++dx) {
        const int yy = py + dy - 1, xx = pxx + dx - 1;
        const bool okp = ((unsigned)yy < 36u) && ((unsigned)xx < 36u);
        offs[dy * 3 + dx] = okp ? (yy * 36 + xx) : 0;
        msk[dy * 3 + dx]  = okp ? 1.f : 0.f;
      }
    const float* __restrict__ inp = in + ((size_t)b * 32 + ciq * 8) * NN;
    const float* __restrict__ wB  = wgt + ((size_t)co * 32 + ciq * 8) * 9;
#pragma unroll
    for (int ci = 0; ci < 8; ++ci) {
      float v[9];
#pragma unroll
      for (int k9 = 0; k9 < 9; ++k9) v[k9] = msk[k9] * inp[ci * NN + offs[k9]];
#pragma unroll
      for (int k9 = 0; k9 < 9; ++k9) acc = fmaf(v[k9], wB[ci * 9 + k9], acc);
    }
  }
  part[ciq][lane] = acc;
  __syncthreads();
  if (threadIdx.x < 64 && ok) {
    float s = part[0][lane] + part[1][lane] + part[2][lane] + part[3][lane]
            + bias[co];
    if (RELU) s = fmaxf(s, 0.f);
    out[((size_t)b * COUT + co) * NN + px] = s;
  }
}

// ---- 9x { reweight -> adaptive Chebyshev solve of (I+uL)x = y } -------------
// One block per (b,c). 324 act threads x 4 row-aligned nodes. Edge weights
// inline from feat. lambda_max via min(Gershgorin 2*d_max, Anderson-Morley
// max_edge(d_i+d_j)). Iteration count: 2*rc^k <= e^-8 (R6-proven), plus
// early-exit when ||r0||inf tiny.
__global__ __launch_bounds__(384) void gtv_k(
    const float* __restrict__ xf, const float* __restrict__ up,
    const float* __restrict__ feat, float* __restrict__ out)
{
  const int sys = blockIdx.x, b = sys / 3, ch = sys % 3;
  const int tid = threadIdx.x;
  const int wave = tid >> 6, lane = tid & 63;
  const bool act = tid < 324;
  const int qq = act ? tid : 0;
  const int i0 = OFF + 4 * qq;

  __shared__ __align__(16) float ysL[TOT], ahL[TOT], avL[TOT],
                                 dA[TOT], dB[TOT], dgL[TOT];
  __shared__ float red[16];

  float u = up[0]; u = fminf(fmaxf(u, 0.001f), 1.0f);

  if (tid < OFF) {
    const int t2 = OFF + NN + tid;
    ysL[tid] = 0.f; ahL[tid] = 0.f; avL[tid] = 0.f;
    dA[tid] = 0.f; dB[tid] = 0.f; dgL[tid] = 0.f;
    ysL[t2] = 0.f; ahL[t2] = 0.f; avL[t2] = 0.f;
    dA[t2] = 0.f; dB[t2] = 0.f; dgL[t2] = 0.f;
  }

  const float* __restrict__ xfB = xf + (size_t)(b * 3 + ch) * NN;
  float wh4[4] = {0.f, 0.f, 0.f, 0.f}, wv4[4] = {0.f, 0.f, 0.f, 0.f};
  if (act) {
    *(float4*)&ysL[i0] = *(const float4*)&xfB[4 * qq];
#pragma unroll
    for (int j = 0; j < 4; ++j) {
      const int n = 4 * qq + j;
      const int col = n % 36, row = n / 36;
      float sh = 0.f, sv = 0.f;
#pragma unroll
      for (int f = 0; f < 6; ++f) {
        const float* __restrict__ fp = feat + (size_t)(b * 6 + f) * NN;
        const float a = fp[n];
        if (col < 35) { const float d = a - fp[n + 1];  sh += d * d; }
        if (row < 35) { const float d = a - fp[n + 36]; sv += d * d; }
      }
      wh4[j] = (col < 35) ? expf(-sh * 1e4f) : 0.f;
      wv4[j] = (row < 35) ? expf(-sv * 1e4f) : 0.f;
    }
  }
  __syncthreads();

  float x[4] = {0.f, 0.f, 0.f, 0.f};

  for (int it = 0; it < 9; ++it) {
    // ---- P1: u-scaled reweighted edge coefficients from current y ----
    float4 yv = make_float4(0,0,0,0);
    float ah[4] = {0,0,0,0}, av[4] = {0,0,0,0};
    if (act) {
      yv = *(const float4*)&ysL[i0];
      const float yR = ysL[i0 + 4];
      const float4 yD = *(const float4*)&ysL[i0 + 36];
      ah[0] = u * wh4[0] / fmaxf(fabsf(yv.x - yv.y), 0.01f);
      ah[1] = u * wh4[1] / fmaxf(fabsf(yv.y - yv.z), 0.01f);
      ah[2] = u * wh4[2] / fmaxf(fabsf(yv.z - yv.w), 0.01f);
      ah[3] = u * wh4[3] / fmaxf(fabsf(yv.w - yR  ), 0.01f);
      av[0] = u * wv4[0] / fmaxf(fabsf(yv.x - yD.x), 0.01f);
      av[1] = u * wv4[1] / fmaxf(fabsf(yv.y - yD.y), 0.01f);
      av[2] = u * wv4[2] / fmaxf(fabsf(yv.z - yD.z), 0.01f);
      av[3] = u * wv4[3] / fmaxf(fabsf(yv.w - yD.w), 0.01f);
      *(float4*)&ahL[i0] = make_float4(ah[0], ah[1], ah[2], ah[3]);
      *(float4*)&avL[i0] = make_float4(av[0], av[1], av[2], av[3]);
    }
    __syncthreads();                                         // B1

    // ---- P2: stencil coeffs, b -> dA, degrees -> dgL, Gershgorin max ----
    float cL[4], cR[4], cU[4], cD[4], cc[4], bn[4], os[4];
    float mo = 0.f;
    if (act) {
      const float cl0 = ahL[i0 - 1];
      const float4 aU = *(const float4*)&avL[i0 - 36];
      cL[0] = cl0;  cL[1] = ah[0]; cL[2] = ah[1]; cL[3] = ah[2];
      cR[0] = ah[0]; cR[1] = ah[1]; cR[2] = ah[2]; cR[3] = ah[3];
      cU[0] = aU.x; cU[1] = aU.y; cU[2] = aU.z; cU[3] = aU.w;
      cD[0] = av[0]; cD[1] = av[1]; cD[2] = av[2]; cD[3] = av[3];
      bn[0] = yv.x; bn[1] = yv.y; bn[2] = yv.z; bn[3] = yv.w;
#pragma unroll
      for (int j = 0; j < 4; ++j) {
        os[j] = cL[j] + cR[j] + cU[j] + cD[j];
        cc[j] = 1.f + os[j];
        mo = fmaxf(mo, os[j]);
      }
      *(float4*)&dA[i0]  = yv;
      *(float4*)&dgL[i0] = make_float4(os[0], os[1], os[2], os[3]);
    } else {
#pragma unroll
      for (int j = 0; j < 4; ++j) {
        cL[j]=cR[j]=cU[j]=cD[j]=0.f; cc[j]=1.f; bn[j]=0.f; os[j]=0.f;
      }
    }
#pragma unroll
    for (int o = 32; o >= 1; o >>= 1) mo = fmaxf(mo, __shfl_xor(mo, o));
    if (lane == 0) red[wave] = mo;
    __syncthreads();                                         // B2

    // ---- P2b: Anderson-Morley edge bound max_edge(d_i + d_j) ----
    float me = 0.f;
    if (act) {
      const float dnx3 = dgL[i0 + 4];
      const float4 dwn = *(const float4*)&dgL[i0 + 36];
      const float dn_[4] = { os[1], os[2], os[3], dnx3 };
      const float dd_[4] = { dwn.x, dwn.y, dwn.z, dwn.w };
#pragma unroll
      for (int j = 0; j < 4; ++j)
        me = fmaxf(me, os[j] + fmaxf(dn_[j], dd_[j]));
    }
#pragma unroll
    for (int o = 32; o >= 1; o >>= 1) me = fmaxf(me, __shfl_xor(me, o));
    if (lane == 0) red[8 + wave] = me;
    __syncthreads();                                         // B3
    if (tid == 0) {
      float m1 = red[0], m2 = red[8];
      for (int w = 1; w < 6; ++w) {
        m1 = fmaxf(m1, red[w]); m2 = fmaxf(m2, red[8 + w]);
      }
      red[14] = fminf(2.f * m1, m2);     // lambda_max(uL) upper bound
    }
    __syncthreads();                                         // B4

    const float lmaxL = red[14];
    const float h     = 0.5f * lmaxL;
    const float theta = 1.f + h;
    const float del   = fmaxf(h, 1e-30f);
    const float sig1  = theta / del;
    const float rho0  = del / theta;
    const float kappa = 1.f + lmaxL;
    const float srk   = sqrtf(kappa);
    const float rc    = (srk - 1.f) / (srk + 1.f);

    // ---- P3: x0 = b, r0 = b - A b, d0 = r0/theta -> dB; ||r0||inf ----
    float r[4], d[4];
    float rmx = 0.f;
    if (act) {
      const float dl = dA[i0 - 1], dr = dA[i0 + 4];
      const float4 u4 = *(const float4*)&dA[i0 - 36];
      const float4 d4 = *(const float4*)&dA[i0 + 36];
      const float uu[4] = {u4.x, u4.y, u4.z, u4.w};
      const float dd[4] = {d4.x, d4.y, d4.z, d4.w};
#pragma unroll
      for (int j = 0; j < 4; ++j) {
        const float nl = (j == 0) ? dl : bn[j - 1];
        const float nr = (j == 3) ? dr : bn[j + 1];
        const float Ab = cc[j] * bn[j] - cL[j] * nl - cR[j] * nr
                       - cU[j] * uu[j] - cD[j] * dd[j];
        x[j] = bn[j];
        r[j] = bn[j] - Ab;
        d[j] = r[j] / theta;
        rmx = fmaxf(rmx, fabsf(r[j]));
      }
      *(float4*)&dB[i0] = make_float4(d[0], d[1], d[2], d[3]);
    } else {
#pragma unroll
      for (int j = 0; j < 4; ++j) { r[j] = 0.f; d[j] = 0.f; x[j] = 0.f; }
    }
#pragma unroll
    for (int o = 32; o >= 1; o >>= 1) rmx = fmaxf(rmx, __shfl_xor(rmx, o));
    if (lane == 0) red[wave] = rmx;
    __syncthreads();                                         // B5
    if (tid == 0) {
      float m = red[0];
      for (int w = 1; w < 6; ++w) m = fmaxf(m, red[w]);
      red[9] = m;
    }
    __syncthreads();                                         // B6

    const float rmax = red[9];
    int kneed;
    if (rmax <= 5e-4f) kneed = 0;                 // already converged
    else if (rc < 1e-10f) kneed = 1;
    else {
      kneed = (int)ceilf(8.0f / (-logf(rc)));    // R6-proven absolute target
      kneed = (kneed < 1) ? 1 : (kneed > KMAX ? KMAX : kneed);
    }

    // ---- P4: Chebyshev 3-term recurrence, halo-only LDS traffic ----
    float rho = rho0;
    float* dc = dB; float* dnx = dA;
    for (int k = 0; k < kneed; ++k) {
      const float rn = 1.f / (2.f * sig1 - rho);
      const float cd = rn * rho, cr = 2.f * rn / del;
      rho = rn;
      if (act) {
        const float dl = dc[i0 - 1], dr = dc[i0 + 4];
        const float4 u4 = *(const float4*)&dc[i0 - 36];
        const float4 d4 = *(const float4*)&dc[i0 + 36];
        const float uu[4] = {u4.x, u4.y, u4.z, u4.w};
        const float dd[4] = {d4.x, d4.y, d4.z, d4.w};
        float dn[4];
#pragma unroll
        for (int j = 0; j < 4; ++j) {
          const float nl = (j == 0) ? dl : d[j - 1];
          const float nr = (j == 3) ? dr : d[j + 1];
          const float Ad = cc[j] * d[j] - cL[j] * nl - cR[j] * nr
                         - cU[j] * uu[j] - cD[j] * dd[j];
          x[j] += d[j];
          r[j] -= Ad;
          dn[j] = cd * d[j] + cr * r[j];
        }
        *(float4*)&dnx[i0] = make_float4(dn[0], dn[1], dn[2], dn[3]);
#pragma unroll
        for (int j = 0; j < 4; ++j) d[j] = dn[j];
      }
      __syncthreads();
      float* t = dc; dc = dnx; dnx = t;
    }

    // ---- commit x as next iteration's y ----
    if (act) *(float4*)&ysL[i0] = make_float4(x[0], x[1], x[2], x[3]);
    __syncthreads();                                         // B7
  }

  if (act) *(float4*)&out[(size_t)(b * 3 + ch) * NN + 4 * qq]
      = make_float4(x[0], x[1], x[2], x[3]);
}

// ----------------------------------------------------------------------------
extern "C" void kernel_launch(void* const* d_in, const int* in_sizes, int n_in,
                              void* d_out, int out_size, void* d_ws, size_t ws_size,
                              hipStream_t stream) {
  const float* xf     = (const float*)d_in[0];   // [2,3,36,36]
  const float* up     = (const float*)d_in[1];   // [1]
  const float* cw_in  = (const float*)d_in[3];   // [32,3,3,3]
  const float* b_in   = (const float*)d_in[4];   // [32]
  const float* cw_mid = (const float*)d_in[5];   // [5,32,32,3,3]
  const float* b_mid  = (const float*)d_in[6];   // [5,32]
  const float* cw_out = (const float*)d_in[7];   // [6,32,3,3]
  const float* b_out  = (const float*)d_in[8];   // [6]

  float* ws   = (float*)d_ws;
  float* hb0  = ws;                   // 2*32*1296 = 82944
  float* hb1  = hb0 + 82944;          // 82944
  float* feat = hb1 + 82944;          // 2*6*1296 = 15552

  conv_in_k<<<dim3(336), dim3(256), 0, stream>>>(xf, cw_in, b_in, hb0);
  const float* src = hb0; float* dst = hb1;
  for (int i = 0; i < 5; ++i) {
    conv_mid2_k<<<dim3(2 * 4 * PXW), dim3(256), 0, stream>>>(
        src, cw_mid + i * 9216, b_mid + i * 32, dst);
    const float* t = dst; dst = (float*)src; src = t;
  }
  conv_mid_k<6, false><<<dim3(2 * 6 * PXW), dim3(256), 0, stream>>>(
      src, cw_out, b_out, feat);

  gtv_k<<<dim3(6), dim3(384), 0, stream>>>(xf, up, feat, (float*)d_out);
}